// Round 8
// baseline (31.364 us; speedup 1.0000x reference)
//
#include <hip/hip_runtime.h>
#include <stdint.h>

// Dynamic 3x3 softmax-weighted conv, reflect padding.
// x: (4, 64, 256, 256) f32, kernel: (4, 9, 256, 256) f32, out: (4, 64, 256, 256) f32

constexpr int BATCH = 4;
constexpr int CHAN  = 64;
constexpr int HH    = 256;
constexpr int WW    = 256;
constexpr int CG    = 4;        // channels per block
constexpr int RPB   = 4;        // output rows per block (one wave per row)
constexpr int NROW  = RPB + 2;  // staged input rows per channel (shared halo)

typedef float vf4 __attribute__((ext_vector_type(4)));

typedef const __attribute__((address_space(1))) void* gas_ptr;
typedef __attribute__((address_space(3))) void* las_ptr;

__global__ __launch_bounds__(256) void dynconv_kernel(
    const float* __restrict__ x,
    const float* __restrict__ ker,
    float* __restrict__ out)
{
    __shared__ float lds[CG][NROW][WW];   // 4*6*256*4B = 24 KiB

    const int t  = threadIdx.x;
    const int rb = t >> 6;          // wave id = output row in band
    const int wq = t & 63;          // lane = float4 slot
    const int w0 = wq * 4;

    const int hband = blockIdx.x;   // 0..63
    const int cg    = blockIdx.y;   // 0..15
    const int b     = blockIdx.z;   // 0..3
    const int h0    = hband * RPB;
    const int h     = h0 + rb;

    const long cs = (long)HH * WW;
    const float* xb = x   + (((long)b * CHAN + cg * CG) * cs);
    float*       ob = out + (((long)b * CHAN + cg * CG) * cs);

    // ---- issue all 24 row-DMAs (6 per wave), zero VGPR held ----
    // slot s of channel ch holds global row reflect(h0-1+s)
    #pragma unroll
    for (int k = 0; k < (CG * NROW) / RPB; ++k) {   // 6 iterations
        const int idx  = k * RPB + rb;              // 0..23, disjoint across waves
        const int ch   = idx / NROW;
        const int slot = idx % NROW;
        int g = h0 - 1 + slot;
        g = (g < 0) ? 1 : ((g > HH - 1) ? HH - 2 : g);
        const float* gsrc = xb + (long)ch * cs + (long)g * WW + w0;  // lane*16B stride
        __builtin_amdgcn_global_load_lds((gas_ptr)gsrc, (las_ptr)&lds[ch][slot][0], 16, 0, 0);
    }

    // ---- kernel loads + softmax overlap the DMA latency ----
    float kv[9][4];
    const long kbase = (((long)b * 9) * HH + h) * WW + w0;
    #pragma unroll
    for (int j = 0; j < 9; ++j) {
        const float4 v = *reinterpret_cast<const float4*>(ker + kbase + (long)j * HH * WW);
        kv[j][0] = v.x; kv[j][1] = v.y; kv[j][2] = v.z; kv[j][3] = v.w;
    }
    #pragma unroll
    for (int p = 0; p < 4; ++p) {
        float m = kv[0][p];
        #pragma unroll
        for (int j = 1; j < 9; ++j) m = fmaxf(m, kv[j][p]);
        float s = 0.f;
        #pragma unroll
        for (int j = 0; j < 9; ++j) { kv[j][p] = __expf(kv[j][p] - m); s += kv[j][p]; }
        const float inv = 1.0f / s;
        #pragma unroll
        for (int j = 0; j < 9; ++j) kv[j][p] *= inv;
    }

    __syncthreads();   // drains DMA (vmcnt) + makes rows visible across waves

    // ---- conv from LDS; wave rb uses slots rb, rb+1, rb+2 ----
    #pragma unroll
    for (int i = 0; i < CG; ++i) {
        float acc0 = 0.f, acc1 = 0.f, acc2 = 0.f, acc3 = 0.f;
        #pragma unroll
        for (int r = 0; r < 3; ++r) {
            const float4 v = *reinterpret_cast<const float4*>(&lds[i][rb + r][w0]);
            float lft = __shfl_up(v.w, 1);
            if (wq == 0)  lft = v.y;     // reflect x[-1] -> x[1]
            float rgt = __shfl_down(v.x, 1);
            if (wq == 63) rgt = v.z;     // reflect x[256] -> x[254]
            const float vals[6] = { lft, v.x, v.y, v.z, v.w, rgt };
            #pragma unroll
            for (int dx = 0; dx < 3; ++dx) {
                const int j = r * 3 + dx;
                acc0 = fmaf(kv[j][0], vals[0 + dx], acc0);
                acc1 = fmaf(kv[j][1], vals[1 + dx], acc1);
                acc2 = fmaf(kv[j][2], vals[2 + dx], acc2);
                acc3 = fmaf(kv[j][3], vals[3 + dx], acc3);
            }
        }
        vf4 o; o.x = acc0; o.y = acc1; o.z = acc2; o.w = acc3;
        __builtin_nontemporal_store(o, reinterpret_cast<vf4*>(ob + (long)i * cs + (long)h * WW + w0));
    }
}

extern "C" void kernel_launch(void* const* d_in, const int* in_sizes, int n_in,
                              void* d_out, int out_size, void* d_ws, size_t ws_size,
                              hipStream_t stream) {
    const float* x   = (const float*)d_in[0];
    const float* ker = (const float*)d_in[1];
    float* out = (float*)d_out;

    dim3 grid(HH / RPB, CHAN / CG, BATCH);  // (64, 16, 4)
    dim3 block(256);
    dynconv_kernel<<<grid, block, 0, stream>>>(x, ker, out);
}